// Round 5
// baseline (1638.342 us; speedup 1.0000x reference)
//
#include <hip/hip_runtime.h>
#include <math.h>

#define VOCAB 50257
#define NCLS 20
#define BATCH 128
#define TLEN 2048

typedef float v4f __attribute__((ext_vector_type(4)));

// Static device scratch (rewritten fully every call; graph-capture safe).
// P layout: [dir][v][lane][4] = {xr + bihr + bhhr, xz + bihz + bhhz, xn + bihn, pad}
__device__ float g_P[(size_t)2 * VOCAB * 256];   // 103 MB
__device__ float g_feats[BATCH * 256];

__device__ __forceinline__ float fsigmoid(float x) {
    return __builtin_amdgcn_rcpf(1.f + __expf(-x));
}
__device__ __forceinline__ float ftanh(float x) {
    float e = __expf(2.f * x);
    return 1.f - 2.f * __builtin_amdgcn_rcpf(e + 1.f);
}

// Load 64 floats as 16 named float4 and PIN them in VGPRs via empty asm.
// The asm def is opaque: the scheduler/RA cannot sink or rematerialize the
// loads into the loop (the R1-R3 failure mode: VGPR_Count stuck at 128-132
// with per-step weight reload on the critical path).
#define LD16_PIN(P, base) \
    v4f P##0  = ((const v4f*)(base))[0],  P##1  = ((const v4f*)(base))[1],  \
        P##2  = ((const v4f*)(base))[2],  P##3  = ((const v4f*)(base))[3],  \
        P##4  = ((const v4f*)(base))[4],  P##5  = ((const v4f*)(base))[5],  \
        P##6  = ((const v4f*)(base))[6],  P##7  = ((const v4f*)(base))[7],  \
        P##8  = ((const v4f*)(base))[8],  P##9  = ((const v4f*)(base))[9],  \
        P##10 = ((const v4f*)(base))[10], P##11 = ((const v4f*)(base))[11], \
        P##12 = ((const v4f*)(base))[12], P##13 = ((const v4f*)(base))[13], \
        P##14 = ((const v4f*)(base))[14], P##15 = ((const v4f*)(base))[15]; \
    asm volatile("" : "+v"(P##0), "+v"(P##1), "+v"(P##2),  "+v"(P##3),      \
                      "+v"(P##4), "+v"(P##5), "+v"(P##6),  "+v"(P##7));     \
    asm volatile("" : "+v"(P##8), "+v"(P##9), "+v"(P##10), "+v"(P##11),     \
                      "+v"(P##12),"+v"(P##13),"+v"(P##14), "+v"(P##15));

// acc = sum_k H_k * W_k over 16 float4, 4 independent chains (issue-bound, not latency-bound)
// accumulator names R##q0..q3 (suffix chosen so no C++ keyword can be formed)
#define DOT16(R, H, W) \
    v4f R##q0 = H##0 * W##0;  v4f R##q1 = H##1 * W##1;                      \
    v4f R##q2 = H##2 * W##2;  v4f R##q3 = H##3 * W##3;                      \
    R##q0 = __builtin_elementwise_fma(H##4,  W##4,  R##q0);                 \
    R##q1 = __builtin_elementwise_fma(H##5,  W##5,  R##q1);                 \
    R##q2 = __builtin_elementwise_fma(H##6,  W##6,  R##q2);                 \
    R##q3 = __builtin_elementwise_fma(H##7,  W##7,  R##q3);                 \
    R##q0 = __builtin_elementwise_fma(H##8,  W##8,  R##q0);                 \
    R##q1 = __builtin_elementwise_fma(H##9,  W##9,  R##q1);                 \
    R##q2 = __builtin_elementwise_fma(H##10, W##10, R##q2);                 \
    R##q3 = __builtin_elementwise_fma(H##11, W##11, R##q3);                 \
    R##q0 = __builtin_elementwise_fma(H##12, W##12, R##q0);                 \
    R##q1 = __builtin_elementwise_fma(H##13, W##13, R##q1);                 \
    R##q2 = __builtin_elementwise_fma(H##14, W##14, R##q2);                 \
    R##q3 = __builtin_elementwise_fma(H##15, W##15, R##q3);

#define HSUM16(R) ({ v4f t_ = (R##q0 + R##q1) + (R##q2 + R##q3); (t_.x + t_.y) + (t_.z + t_.w); })

// ---------------- Kernel A: P[dir][v][lane] = {emb[v]·wih_r + br', emb[v]·wih_z + bz', emb[v]·wih_n + bn_ih, 0}
__global__ __launch_bounds__(128)
__attribute__((amdgpu_waves_per_eu(1, 1)))
void precompute_P(
    const float* __restrict__ emb,
    const float* __restrict__ wih_f, const float* __restrict__ bih_f, const float* __restrict__ bhh_f,
    const float* __restrict__ wih_b, const float* __restrict__ bih_b, const float* __restrict__ bhh_b)
{
    const int lane = threadIdx.x & 63;
    const int dir  = threadIdx.x >> 6;          // wave-uniform
    const float* wih = dir ? wih_b : wih_f;
    const float* bih = dir ? bih_b : bih_f;
    const float* bhh = dir ? bhh_b : bhh_f;

    LD16_PIN(wr, wih + (size_t)lane * 64)
    LD16_PIN(wz, wih + (size_t)(64 + lane) * 64)
    LD16_PIN(wn, wih + (size_t)(128 + lane) * 64)
    const float br = bih[lane] + bhh[lane];            // fold bhh_r / bhh_z here
    const float bz = bih[64 + lane] + bhh[64 + lane];
    const float bn = bih[128 + lane];                  // bhh_n stays separate (scaled by r)

    float4* Pd = (float4*)g_P + (size_t)dir * VOCAB * 64;

    for (int v = blockIdx.x; v < VOCAB; v += gridDim.x) {
        const v4f* e4 = (const v4f*)(emb + (size_t)v * 64);   // wave-uniform -> scalar loads
        const v4f h0 = e4[0],  h1 = e4[1],  h2 = e4[2],  h3 = e4[3],
                  h4 = e4[4],  h5 = e4[5],  h6 = e4[6],  h7 = e4[7],
                  h8 = e4[8],  h9 = e4[9],  h10 = e4[10], h11 = e4[11],
                  h12 = e4[12], h13 = e4[13], h14 = e4[14], h15 = e4[15];
        DOT16(ar, h, wr)
        DOT16(az, h, wz)
        DOT16(an, h, wn)
        float4 o;
        o.x = HSUM16(ar) + br;
        o.y = HSUM16(az) + bz;
        o.z = HSUM16(an) + bn;
        o.w = 0.f;
        Pd[(size_t)v * 64 + lane] = o;                 // 64 lanes x 16B contiguous
    }
}

// ---------------- Kernel B: one wave per (dir,batch); no barriers; pinned weights; 4-deep prefetch
__global__ __launch_bounds__(64)
__attribute__((amdgpu_waves_per_eu(1, 1)))
void gru_seq(
    const int* __restrict__ tokens,
    const float* __restrict__ whh_f, const float* __restrict__ bhh_f,
    const float* __restrict__ whh_b, const float* __restrict__ bhh_b)
{
    const int lane = threadIdx.x;                 // hidden unit
    const int b = blockIdx.x >> 1;
    const int dir = blockIdx.x & 1;
    const float* whh = dir ? whh_b : whh_f;
    const float* bhh = dir ? bhh_b : bhh_f;
    const float4* P4 = (const float4*)g_P + (size_t)dir * VOCAB * 64;

    __shared__ __align__(16) float h_lds[64];
    __shared__ int tok_lds[TLEN];
    for (int t = lane; t < TLEN; t += 64) tok_lds[t] = tokens[b * TLEN + t];
    // single-wave block: lockstep; NO __syncthreads (would force vmcnt(0) drain per step).

    // 192 weight floats pinned in VGPRs (asm defs: cannot be sunk/remat'd back into the loop)
    LD16_PIN(wr, whh + (size_t)lane * 64)
    LD16_PIN(wz, whh + (size_t)(64 + lane) * 64)
    LD16_PIN(wn, whh + (size_t)(128 + lane) * 64)
    const float bn = bhh[128 + lane];

    h_lds[lane] = 0.f;
    float h = 0.f, sum = 0.f, mx = -INFINITY;

    auto rowAt = [&](int s) -> const float4* {
        int ss = s < TLEN ? s : TLEN - 1;               // clamp tail prefetches (values unused)
        int tok = tok_lds[dir ? (TLEN - 1 - ss) : ss];
        return P4 + (size_t)tok * 64;
    };

    float4 xg[4];
#pragma unroll
    for (int j = 0; j < 4; j++) xg[j] = rowAt(j)[lane];

    for (int s = 0; s < TLEN; s += 4) {
#pragma unroll
        for (int j = 0; j < 4; j++) {
            const float4 cur = xg[j];
            // prefetch step s+j+4: consumed 4 sub-steps later -> covers gather latency
            xg[j] = rowAt(s + j + 4)[lane];

            const v4f* hp = (const v4f*)h_lds;          // uniform-address reads = broadcast
            const v4f h0 = hp[0],  h1 = hp[1],  h2 = hp[2],  h3 = hp[3],
                      h4 = hp[4],  h5 = hp[5],  h6 = hp[6],  h7 = hp[7],
                      h8 = hp[8],  h9 = hp[9],  h10 = hp[10], h11 = hp[11],
                      h12 = hp[12], h13 = hp[13], h14 = hp[14], h15 = hp[15];
            DOT16(ar, h, wr)
            DOT16(az, h, wz)
            DOT16(an, h, wn)
            const float hr = HSUM16(ar), hz = HSUM16(az), hn = HSUM16(an);

            const float r = fsigmoid(cur.x + hr);       // biases pre-folded into P
            const float z = fsigmoid(cur.y + hz);
            const float n = ftanh(cur.z + r * (hn + bn));
            h = fmaf(z, h - n, n);                      // (1-z)*n + z*h
            sum += h;
            mx = fmaxf(mx, h);

            __builtin_amdgcn_wave_barrier();            // scheduling fence only (no s_barrier)
            h_lds[lane] = h;
            __builtin_amdgcn_wave_barrier();
        }
    }

    g_feats[b * 256 + dir * 64 + lane] = sum * (1.f / TLEN);
    g_feats[b * 256 + 128 + dir * 64 + lane] = mx;
}

// ---------------- Kernel C: classifier  out = W2 @ gelu(W1 @ feats + b1) + b2
__global__ __launch_bounds__(64) void classifier(
    const float* __restrict__ w1, const float* __restrict__ b1,
    const float* __restrict__ w2, const float* __restrict__ b2,
    float* __restrict__ out)
{
    const int b = blockIdx.x;
    const int i = threadIdx.x;
    __shared__ float f[256];
    __shared__ float hid[64];
    for (int c = i; c < 256; c += 64) f[c] = g_feats[b * 256 + c];
    __syncthreads();

    float acc = b1[i];
    const float* wrow = w1 + (size_t)i * 256;
#pragma unroll 16
    for (int c = 0; c < 256; c++) acc = fmaf(f[c], wrow[c], acc);
    hid[i] = acc * 0.5f * (1.f + erff(acc * 0.70710678118654752f));   // exact GELU
    __syncthreads();

    if (i < NCLS) {
        float o = b2[i];
        const float* w2r = w2 + (size_t)i * 64;
#pragma unroll
        for (int j = 0; j < 64; j++) o = fmaf(hid[j], w2r[j], o);
        out[b * NCLS + i] = o;
    }
}

extern "C" void kernel_launch(void* const* d_in, const int* in_sizes, int n_in,
                              void* d_out, int out_size, void* d_ws, size_t ws_size,
                              hipStream_t stream) {
    const int*   tokens = (const int*)  d_in[0];
    const float* emb    = (const float*)d_in[1];
    const float* wih_f  = (const float*)d_in[2];
    const float* whh_f  = (const float*)d_in[3];
    const float* bih_f  = (const float*)d_in[4];
    const float* bhh_f  = (const float*)d_in[5];
    const float* wih_b  = (const float*)d_in[6];
    const float* whh_b  = (const float*)d_in[7];
    const float* bih_b  = (const float*)d_in[8];
    const float* bhh_b  = (const float*)d_in[9];
    const float* w1     = (const float*)d_in[10];
    const float* b1     = (const float*)d_in[11];
    const float* w2     = (const float*)d_in[12];
    const float* b2     = (const float*)d_in[13];
    float* out = (float*)d_out;

    precompute_P<<<1024, 128, 0, stream>>>(emb, wih_f, bih_f, bhh_f, wih_b, bih_b, bhh_b);
    gru_seq<<<2 * BATCH, 64, 0, stream>>>(tokens, whh_f, bhh_f, whh_b, bhh_b);
    classifier<<<BATCH, 64, 0, stream>>>(w1, b1, w2, b2, out);
}